// Round 5
// baseline (45.611 us; speedup 1.0000x reference)
//
#include <hip/hip_runtime.h>

// TopKRouter: x[B=16,C=768,H=64,W=64] fp32, W[E=16,C=768], b[E=16], k=2.
// R5: two-kernel (Wt transpose prologue kept — proven in R4) but main kernel
// restructured for TLP: 1 pixel/lane, block = 64 px x 4 channel-groups,
// grid = 1024 blocks = 4 blocks/CU = 16 waves/CU (was 2 blocks/8 waves).
// acc = 16 VGPR -> deep load pipeline at unroll 4.
// Outputs fp32 concat: topk_probs[16,2,64,64] | topk_indices[16,2,64,64] |
// scores[16,16,64,64].

#define C_DIM 768
#define E_DIM 16
#define HW    4096   // 64*64
#define NPIX  65536  // 16*4096

// ---------------- Prologue: Wt[c][e] = W[e][c] ----------------------------
__global__ __launch_bounds__(256) void transpose_w(
    const float* __restrict__ Wm, float* __restrict__ Wt)
{
    const int t = blockIdx.x * 256 + threadIdx.x;  // 12288 elements
    if (t < C_DIM * E_DIM) {
        const int c = t >> 4, e = t & 15;
        Wt[t] = Wm[e * C_DIM + c];
    }
}

// ---------------- Fused main ----------------------------------------------
__global__ __launch_bounds__(256) void router_main(
    const float* __restrict__ x,     // [B, C, HW]
    const float* __restrict__ Wt,    // [C, E] transposed weights (in ws)
    const float* __restrict__ bias,  // [E]
    float* __restrict__ out)
{
    __shared__ float lds[4][64][17];  // [cg][px][e], pad 17 -> conflict-free

    const int p0 = blockIdx.x * 64;              // first pixel of block
    const int b  = p0 >> 12;                     // batch (block-uniform)
    const int pb = p0 & 4095;
    const int cg = __builtin_amdgcn_readfirstlane(threadIdx.x >> 6);
    const int ln = threadIdx.x & 63;             // lane -> pixel
    const int c0 = cg * 192;

    const float* xp = x + (size_t)b * C_DIM * HW + pb + ln;

    float acc[E_DIM];
#pragma unroll
    for (int e = 0; e < E_DIM; ++e) acc[e] = 0.0f;

#pragma unroll 4
    for (int c = c0; c < c0 + 192; ++c) {
        const float xv = xp[(size_t)c * HW];
        const float4* wt = reinterpret_cast<const float4*>(Wt + c * E_DIM);
        const float4 w0 = wt[0], w1 = wt[1], w2 = wt[2], w3 = wt[3];
        acc[ 0] = fmaf(xv, w0.x, acc[ 0]);
        acc[ 1] = fmaf(xv, w0.y, acc[ 1]);
        acc[ 2] = fmaf(xv, w0.z, acc[ 2]);
        acc[ 3] = fmaf(xv, w0.w, acc[ 3]);
        acc[ 4] = fmaf(xv, w1.x, acc[ 4]);
        acc[ 5] = fmaf(xv, w1.y, acc[ 5]);
        acc[ 6] = fmaf(xv, w1.z, acc[ 6]);
        acc[ 7] = fmaf(xv, w1.w, acc[ 7]);
        acc[ 8] = fmaf(xv, w2.x, acc[ 8]);
        acc[ 9] = fmaf(xv, w2.y, acc[ 9]);
        acc[10] = fmaf(xv, w2.z, acc[10]);
        acc[11] = fmaf(xv, w2.w, acc[11]);
        acc[12] = fmaf(xv, w3.x, acc[12]);
        acc[13] = fmaf(xv, w3.y, acc[13]);
        acc[14] = fmaf(xv, w3.z, acc[14]);
        acc[15] = fmaf(xv, w3.w, acc[15]);
    }

    // stage partials: [cg][pixel][e] (lane stride 17 floats -> 2 lanes/bank, free)
#pragma unroll
    for (int e = 0; e < E_DIM; ++e) lds[cg][ln][e] = acc[e];
    __syncthreads();

    const int t = threadIdx.x;
    if (t < 64) {
        const int p = pb + t;  // pixel within b-plane

        float lg[E_DIM];
#pragma unroll
        for (int e = 0; e < E_DIM; ++e)
            lg[e] = bias[e] + lds[0][t][e] + lds[1][t][e] + lds[2][t][e] + lds[3][t][e];

        float m = -INFINITY;
#pragma unroll
        for (int e = 0; e < E_DIM; ++e) m = fmaxf(m, lg[e]);
        float pr[E_DIM];
        float sum = 0.0f;
#pragma unroll
        for (int e = 0; e < E_DIM; ++e) {
            pr[e] = __expf(lg[e] - m);
            sum += pr[e];
        }
        const float inv = 1.0f / sum;

        float* scores = out + 262144;
#pragma unroll
        for (int e = 0; e < E_DIM; ++e) {
            const float s = pr[e] * inv;
            pr[e] = s;
            scores[(size_t)(b * E_DIM + e) * HW + p] = s;
        }

        // top-2, ties -> lower index (matches jax.lax.top_k)
        int i1 = 0;
        float p1 = pr[0];
#pragma unroll
        for (int e = 1; e < E_DIM; ++e)
            if (pr[e] > p1) { p1 = pr[e]; i1 = e; }
        int i2 = -1;
        float p2 = -INFINITY;
#pragma unroll
        for (int e = 0; e < E_DIM; ++e)
            if (e != i1 && pr[e] > p2) { p2 = pr[e]; i2 = e; }

        const float rs = 1.0f / (p1 + p2);
        const size_t o1 = (size_t)(b * 2 + 0) * HW + p;
        const size_t o2 = (size_t)(b * 2 + 1) * HW + p;
        out[o1] = p1 * rs;
        out[o2] = p2 * rs;
        float* idxo = out + 131072;
        idxo[o1] = (float)i1;
        idxo[o2] = (float)i2;
    }
}

// ---------------- Fallback: fused single-pass, no ws ----------------------
__global__ __launch_bounds__(256) void topk_router_fused(
    const float* __restrict__ x, const float* __restrict__ Wm,
    const float* __restrict__ bias, float* __restrict__ out)
{
    const int g = blockIdx.x * 256 + threadIdx.x;
    const int b = g >> 12;
    const int p = g & 4095;
    const float* xp = x + (size_t)b * C_DIM * HW + p;

    float acc[E_DIM];
#pragma unroll
    for (int e = 0; e < E_DIM; ++e) acc[e] = 0.0f;
#pragma unroll 16
    for (int c = 0; c < C_DIM; ++c) {
        const float xv = xp[(size_t)c * HW];
#pragma unroll
        for (int e = 0; e < E_DIM; ++e)
            acc[e] = fmaf(xv, Wm[e * C_DIM + c], acc[e]);
    }
    float m = -INFINITY;
#pragma unroll
    for (int e = 0; e < E_DIM; ++e) { acc[e] += bias[e]; m = fmaxf(m, acc[e]); }
    float pr[E_DIM]; float sum = 0.0f;
#pragma unroll
    for (int e = 0; e < E_DIM; ++e) { pr[e] = __expf(acc[e] - m); sum += pr[e]; }
    const float inv = 1.0f / sum;
    float* scores = out + 262144;
#pragma unroll
    for (int e = 0; e < E_DIM; ++e) {
        const float s = pr[e] * inv; pr[e] = s;
        scores[(size_t)(b * E_DIM + e) * HW + p] = s;
    }
    int i1 = 0; float p1 = pr[0];
#pragma unroll
    for (int e = 1; e < E_DIM; ++e) if (pr[e] > p1) { p1 = pr[e]; i1 = e; }
    int i2 = -1; float p2 = -INFINITY;
#pragma unroll
    for (int e = 0; e < E_DIM; ++e) if (e != i1 && pr[e] > p2) { p2 = pr[e]; i2 = e; }
    const float rs = 1.0f / (p1 + p2);
    const size_t o1 = (size_t)(b * 2 + 0) * HW + p;
    const size_t o2 = (size_t)(b * 2 + 1) * HW + p;
    out[o1] = p1 * rs; out[o2] = p2 * rs;
    float* idxo = out + 131072;
    idxo[o1] = (float)i1; idxo[o2] = (float)i2;
}

extern "C" void kernel_launch(void* const* d_in, const int* in_sizes, int n_in,
                              void* d_out, int out_size, void* d_ws, size_t ws_size,
                              hipStream_t stream) {
    const float* x  = (const float*)d_in[0];
    const float* Wm = (const float*)d_in[1];
    const float* bs = (const float*)d_in[2];
    float* out = (float*)d_out;
    float* Wt  = (float*)d_ws;  // 48 KB

    if (ws_size >= (size_t)C_DIM * E_DIM * sizeof(float)) {
        transpose_w<<<48, 256, 0, stream>>>(Wm, Wt);
        router_main<<<NPIX / 64, 256, 0, stream>>>(x, Wt, bs, out);
    } else {
        topk_router_fused<<<NPIX / 256, 256, 0, stream>>>(x, Wm, bs, out);
    }
}